// Round 6
// baseline (320.031 us; speedup 1.0000x reference)
//
#include <hip/hip_runtime.h>

constexpr int IN_F = 128;
constexpr int NH   = 4;    // heads
constexpr int ND   = 32;   // dim per head
constexpr int HD   = 128;  // NH*ND
constexpr float NEG_SLOPE = 0.2f;

using short8 = __attribute__((ext_vector_type(8))) short;
using f32x4  = __attribute__((ext_vector_type(4))) float;

__device__ inline unsigned bf16b(float f) {  // f32 -> bf16 bits, RNE
  unsigned u = __float_as_uint(f);
  return (u + 0x7FFFu + ((u >> 16) & 1u)) >> 16;
}

// ---- Kernel A: MFMA GEMM  ft(bf16-pair-packed) + el/er fused as extra cols -
// (unchanged from round 5)
__global__ __launch_bounds__(256) void k_gemm(
    const float* __restrict__ feat, const float* __restrict__ W,
    const float* __restrict__ attn_l, const float* __restrict__ attn_r,
    unsigned* __restrict__ ftb2, float* __restrict__ el, float* __restrict__ er,
    int n) {
  __shared__ unsigned sB[144 * 64];  // 36864 B (uint = 2 bf16)
  const int t = threadIdx.x;

  for (int item = t; item < 144 * 16; item += 256) {
    const int r = item >> 4, s = item & 15;
    const int k0 = s * 8;
    unsigned pk[4];
    if (r < HD) {
#pragma unroll
      for (int j2 = 0; j2 < 4; ++j2) {
        const unsigned lo = bf16b(W[(size_t)(k0 + 2 * j2) * HD + r]);
        const unsigned hi = bf16b(W[(size_t)(k0 + 2 * j2 + 1) * HD + r]);
        pk[j2] = lo | (hi << 16);
      }
    } else if (r < HD + 8) {
      const int j8 = r - HD;
      const int h = j8 & 3;
      const float* av = (j8 < 4 ? attn_l : attn_r) + h * ND;
      float sums[8];
#pragma unroll
      for (int j = 0; j < 8; ++j) {
        const float4* wv = (const float4*)&W[(size_t)(k0 + j) * HD + h * ND];
        const float4* a4 = (const float4*)av;
        float sum = 0.f;
#pragma unroll
        for (int c4 = 0; c4 < ND / 4; ++c4) {
          const float4 w = wv[c4], a = a4[c4];
          sum += w.x * a.x + w.y * a.y + w.z * a.z + w.w * a.w;
        }
        sums[j] = sum;
      }
#pragma unroll
      for (int j2 = 0; j2 < 4; ++j2)
        pk[j2] = bf16b(sums[2 * j2]) | (bf16b(sums[2 * j2 + 1]) << 16);
    } else {
      pk[0] = pk[1] = pk[2] = pk[3] = 0;
    }
    unsigned* dp = &sB[r * 64 + ((s ^ (r & 7)) << 2)];
    *(uint4*)dp = make_uint4(pk[0], pk[1], pk[2], pk[3]);
  }
  __syncthreads();

  const int lane = t & 63;
  const int wv   = t >> 6;
  const int r0   = blockIdx.x * 128 + wv * 32;
  if (r0 >= n) return;
  const int lrow = lane & 15;
  const int lk   = lane >> 4;

  f32x4 acc[2][9];
#pragma unroll
  for (int st = 0; st < 2; ++st)
#pragma unroll
    for (int ct = 0; ct < 9; ++ct) acc[st][ct] = (f32x4)0.f;

#pragma unroll
  for (int ks = 0; ks < 4; ++ks) {
    short8 b[9];
#pragma unroll
    for (int ct = 0; ct < 9; ++ct) {
      const int row = ct * 16 + lrow;
      const int slot = ks * 4 + lk;
      b[ct] = *(const short8*)&sB[row * 64 + ((slot ^ (row & 7)) << 2)];
    }
#pragma unroll
    for (int st = 0; st < 2; ++st) {
      int arow = r0 + st * 16 + lrow;
      arow = arow < n ? arow : n - 1;
      const float* ap = feat + (size_t)arow * IN_F + ks * 32 + lk * 8;
      const float4 f0 = *(const float4*)ap;
      const float4 f1 = *(const float4*)(ap + 4);
      short8 a;
      a[0] = (short)bf16b(f0.x); a[1] = (short)bf16b(f0.y);
      a[2] = (short)bf16b(f0.z); a[3] = (short)bf16b(f0.w);
      a[4] = (short)bf16b(f1.x); a[5] = (short)bf16b(f1.y);
      a[6] = (short)bf16b(f1.z); a[7] = (short)bf16b(f1.w);
#pragma unroll
      for (int ct = 0; ct < 9; ++ct)
        acc[st][ct] = __builtin_amdgcn_mfma_f32_16x16x32_bf16(a, b[ct], acc[st][ct], 0, 0, 0);
    }
  }

#pragma unroll
  for (int st = 0; st < 2; ++st) {
#pragma unroll
    for (int i = 0; i < 4; ++i) {
      const int r = r0 + st * 16 + lk * 4 + i;
      if (r >= n) continue;
#pragma unroll
      for (int ct = 0; ct < 4; ++ct) {
        const unsigned pk = bf16b(acc[st][ct][i]) | (bf16b(acc[st][ct + 4][i]) << 16);
        ftb2[(size_t)r * 64 + ct * 16 + lrow] = pk;
      }
      if (lrow < 4)      el[r * NH + lrow]     = acc[st][8][i];
      else if (lrow < 8) er[r * NH + lrow - 4] = acc[st][8][i];
    }
  }
}

// ---- Kernel R: rank[e] = atomicAdd(deg[dst[e]],1), 4 edges/thread ---------
__global__ __launch_bounds__(256) void k_rank(
    const int* __restrict__ dst, int* __restrict__ deg, int* __restrict__ rank,
    int ne) {
  const int e4 = (blockIdx.x * 256 + threadIdx.x) * 4;
  if (e4 + 4 <= ne) {
    const int4 d = *(const int4*)(dst + e4);
    int4 r;
    r.x = atomicAdd(deg + d.x, 1);
    r.y = atomicAdd(deg + d.y, 1);
    r.z = atomicAdd(deg + d.z, 1);
    r.w = atomicAdd(deg + d.w, 1);
    *(int4*)(rank + e4) = r;
  } else {
    for (int e = e4; e < ne; ++e) rank[e] = atomicAdd(deg + dst[e], 1);
  }
}

// ---------------- Scan: exclusive prefix over deg (3 kernels) --------------
__global__ __launch_bounds__(256) void k_scan1(
    const int* __restrict__ deg, int* __restrict__ pexcl,
    int* __restrict__ bsum, int n) {
  const int t = threadIdx.x;
  const int base = blockIdx.x * 1024 + t * 4;
  int v0 = base + 0 < n ? deg[base + 0] : 0;
  int v1 = base + 1 < n ? deg[base + 1] : 0;
  int v2 = base + 2 < n ? deg[base + 2] : 0;
  int v3 = base + 3 < n ? deg[base + 3] : 0;
  const int s = v0 + v1 + v2 + v3;
  const int lane = t & 63, w = t >> 6;
  int x = s;
#pragma unroll
  for (int off = 1; off < 64; off <<= 1) {
    int y = __shfl_up(x, off);
    if (lane >= off) x += y;
  }
  __shared__ int ws[4];
  if (lane == 63) ws[w] = x;
  __syncthreads();
  int woff = 0;
  for (int i = 0; i < w; ++i) woff += ws[i];
  int run = woff + x - s;
  if (base + 0 < n) { pexcl[base + 0] = run; run += v0; }
  if (base + 1 < n) { pexcl[base + 1] = run; run += v1; }
  if (base + 2 < n) { pexcl[base + 2] = run; run += v2; }
  if (base + 3 < n) { pexcl[base + 3] = run; run += v3; }
  if (t == 0) bsum[blockIdx.x] = ws[0] + ws[1] + ws[2] + ws[3];
}

__global__ __launch_bounds__(256) void k_scan2(
    const int* __restrict__ bsum, int* __restrict__ boff, int B) {
  const int t = threadIdx.x;
  const int s = t < B ? bsum[t] : 0;
  const int lane = t & 63, w = t >> 6;
  int x = s;
#pragma unroll
  for (int off = 1; off < 64; off <<= 1) {
    int y = __shfl_up(x, off);
    if (lane >= off) x += y;
  }
  __shared__ int ws[4];
  if (lane == 63) ws[w] = x;
  __syncthreads();
  int woff = 0;
  for (int i = 0; i < w; ++i) woff += ws[i];
  if (t < B) boff[t] = woff + x - s;
}

__global__ __launch_bounds__(256) void k_scan3(
    const int* __restrict__ pexcl, const int* __restrict__ boff,
    int* __restrict__ offsets, int n, int ne) {
  const int i = blockIdx.x * 256 + threadIdx.x;
  if (i < n) offsets[i] = pexcl[i] + boff[i >> 10];
  if (i == 0) offsets[n] = ne;
}

// ---- Kernel S: scatter src + UNNORMALIZED softmax weights into CSR order --
// palpha[pos] = (p0, p2, p1, p3) so half-wave hsel reads its float2 directly.
__global__ __launch_bounds__(256) void k_scatter(
    const int* __restrict__ src, const int* __restrict__ dst,
    const int* __restrict__ rank, const int* __restrict__ offsets,
    const float* __restrict__ el, const float* __restrict__ er,
    int* __restrict__ src_sorted, float* __restrict__ palpha, int ne) {
  const int e = blockIdx.x * 256 + threadIdx.x;
  if (e >= ne) return;
  const int s = src[e], d = dst[e];
  const int pos = offsets[d] + rank[e];
  src_sorted[pos] = s;
  const float4 l = *(const float4*)(el + (size_t)s * NH);
  const float4 r = *(const float4*)(er + (size_t)d * NH);
  float e0 = l.x + r.x, e1 = l.y + r.y, e2 = l.z + r.z, e3 = l.w + r.w;
  e0 = e0 > 0.f ? e0 : NEG_SLOPE * e0;
  e1 = e1 > 0.f ? e1 : NEG_SLOPE * e1;
  e2 = e2 > 0.f ? e2 : NEG_SLOPE * e2;
  e3 = e3 > 0.f ? e3 : NEG_SLOPE * e3;
  // |logits| <= ~8: exp() safe without segment-max; ratio identical
  *(float4*)(palpha + (size_t)pos * NH) =
      make_float4(__expf(e0), __expf(e2), __expf(e1), __expf(e3));
}

// ------ Kernel D: aggregation, one wave per dst node -----------------------
__global__ __launch_bounds__(256) void k_aggr(
    const int* __restrict__ offsets, const int* __restrict__ src_sorted,
    const float* __restrict__ palpha, const unsigned* __restrict__ ftb2,
    float* __restrict__ out, int n) {
  const int wid = (blockIdx.x * 256 + threadIdx.x) >> 6;
  if (wid >= n) return;
  const int lane = threadIdx.x & 63;
  const int hsel = lane >> 5;  // elem 'lane' -> head hsel; elem lane+64 -> 2+hsel
  const int start = offsets[wid], end = offsets[wid + 1];
  float acc0 = 0.f, acc1 = 0.f, den0 = 0.f, den1 = 0.f;

  int i = start;
  for (; i + 2 <= end; i += 2) {
    const int sA = src_sorted[i], sB = src_sorted[i + 1];
    const float2 pA = *(const float2*)(palpha + (size_t)i * NH + (hsel << 1));
    const float2 pB = *(const float2*)(palpha + (size_t)(i + 1) * NH + (hsel << 1));
    const unsigned vA = ftb2[(size_t)sA * 64 + lane];
    const unsigned vB = ftb2[(size_t)sB * 64 + lane];
    acc0 += __uint_as_float(vA << 16) * pA.x + __uint_as_float(vB << 16) * pB.x;
    acc1 += __uint_as_float(vA & 0xFFFF0000u) * pA.y +
            __uint_as_float(vB & 0xFFFF0000u) * pB.y;
    den0 += pA.x + pB.x;
    den1 += pA.y + pB.y;
  }
  if (i < end) {
    const int s = src_sorted[i];
    const float2 pv = *(const float2*)(palpha + (size_t)i * NH + (hsel << 1));
    const unsigned v = ftb2[(size_t)s * 64 + lane];
    acc0 += __uint_as_float(v << 16) * pv.x;
    acc1 += __uint_as_float(v & 0xFFFF0000u) * pv.y;
    den0 += pv.x;
    den1 += pv.y;
  }
  den0 = den0 > 0.f ? den0 : 1.f;  // isolated-node guard (matches reference)
  den1 = den1 > 0.f ? den1 : 1.f;
  float* orow = out + (size_t)wid * HD;
  orow[lane] = acc0 / den0;
  orow[64 + lane] = acc1 / den1;
}

extern "C" void kernel_launch(void* const* d_in, const int* in_sizes, int n_in,
                              void* d_out, int out_size, void* d_ws, size_t ws_size,
                              hipStream_t stream) {
  const float* feat   = (const float*)d_in[0];
  const float* W      = (const float*)d_in[1];
  const float* attn_l = (const float*)d_in[2];
  const float* attn_r = (const float*)d_in[3];
  const int*   src    = (const int*)d_in[4];
  const int*   dst    = (const int*)d_in[5];
  const int n  = in_sizes[0] / IN_F;
  const int ne = in_sizes[4];
  float* out = (float*)d_out;

  // workspace layout (16B-aligned blocks first)
  char* wp = (char*)d_ws;
  unsigned* ftb2    = (unsigned*)wp; wp += (size_t)n * 64 * 4;    // 25.6 MB
  float* palpha     = (float*)wp;    wp += (size_t)ne * NH * 4;   // 25.6 MB
  float* el         = (float*)wp;    wp += (size_t)n * NH * 4;
  float* er         = (float*)wp;    wp += (size_t)n * NH * 4;
  int*   rank       = (int*)wp;      wp += (size_t)ne * 4;
  int*   src_sorted = (int*)wp;      wp += (size_t)ne * 4;
  int*   deg        = (int*)wp;      wp += (size_t)n * 4;
  int*   pexcl      = (int*)wp;      wp += (size_t)n * 4;
  int*   offsets    = (int*)wp;      wp += (size_t)(n + 1) * 4;
  int*   bsum       = (int*)wp;      wp += 256 * 4;
  int*   boff       = (int*)wp;      wp += 256 * 4;

  hipMemsetAsync(deg, 0, (size_t)n * 4, stream);

  const int B = (n + 1023) / 1024;
  k_gemm<<<(n + 127) / 128, 256, 0, stream>>>(feat, W, attn_l, attn_r, ftb2, el, er, n);
  k_rank<<<(ne + 1023) / 1024, 256, 0, stream>>>(dst, deg, rank, ne);
  k_scan1<<<B, 256, 0, stream>>>(deg, pexcl, bsum, n);
  k_scan2<<<1, 256, 0, stream>>>(bsum, boff, B);
  k_scan3<<<(n + 255) / 256, 256, 0, stream>>>(pexcl, boff, offsets, n, ne);
  k_scatter<<<(ne + 255) / 256, 256, 0, stream>>>(src, dst, rank, offsets, el, er,
                                                  src_sorted, palpha, ne);
  k_aggr<<<(n + 3) / 4, 256, 0, stream>>>(offsets, src_sorted, palpha, ftb2, out, n);
}

// Round 7
// 231.753 us; speedup vs baseline: 1.3809x; 1.3809x over previous
//
#include <hip/hip_runtime.h>
#include <hip/hip_fp16.h>

constexpr int IN_F = 128;
constexpr int NH   = 4;    // heads
constexpr int ND   = 32;   // dim per head
constexpr int HD   = 128;  // NH*ND
constexpr float NEG_SLOPE = 0.2f;

using short8 = __attribute__((ext_vector_type(8))) short;
using f32x4  = __attribute__((ext_vector_type(4))) float;

__device__ inline unsigned bf16b(float f) {  // f32 -> bf16 bits, RNE
  unsigned u = __float_as_uint(f);
  return (u + 0x7FFFu + ((u >> 16) & 1u)) >> 16;
}

// ---- Kernel P: one-shot build of swizzled bf16 W^T-extended tile ----------
// wtx rows 0..127: W^T; rows 128..135: (W@[AL|AR])^T (el h0..3, er h0..3);
// rows 136..143: zero. 16B slots XOR-swizzled: slot_stored = slot ^ (row&7).
__global__ __launch_bounds__(256) void k_prep(
    const float* __restrict__ W, const float* __restrict__ attn_l,
    const float* __restrict__ attn_r, unsigned* __restrict__ wtx) {
  const int item = blockIdx.x * 256 + threadIdx.x;
  if (item >= 144 * 16) return;
  const int r = item >> 4, s = item & 15;
  const int k0 = s * 8;
  unsigned pk[4];
  if (r < HD) {
#pragma unroll
    for (int j2 = 0; j2 < 4; ++j2) {
      const unsigned lo = bf16b(W[(size_t)(k0 + 2 * j2) * HD + r]);
      const unsigned hi = bf16b(W[(size_t)(k0 + 2 * j2 + 1) * HD + r]);
      pk[j2] = lo | (hi << 16);
    }
  } else if (r < HD + 8) {
    const int j8 = r - HD;
    const int h = j8 & 3;
    const float* av = (j8 < 4 ? attn_l : attn_r) + h * ND;
    float sums[8];
#pragma unroll
    for (int j = 0; j < 8; ++j) {
      const float4* wv = (const float4*)&W[(size_t)(k0 + j) * HD + h * ND];
      const float4* a4 = (const float4*)av;
      float sum = 0.f;
#pragma unroll
      for (int c4 = 0; c4 < ND / 4; ++c4) {
        const float4 w = wv[c4], a = a4[c4];
        sum += w.x * a.x + w.y * a.y + w.z * a.z + w.w * a.w;
      }
      sums[j] = sum;
    }
#pragma unroll
    for (int j2 = 0; j2 < 4; ++j2)
      pk[j2] = bf16b(sums[2 * j2]) | (bf16b(sums[2 * j2 + 1]) << 16);
  } else {
    pk[0] = pk[1] = pk[2] = pk[3] = 0;
  }
  *(uint4*)&wtx[r * 64 + ((s ^ (r & 7)) << 2)] = make_uint4(pk[0], pk[1], pk[2], pk[3]);
}

// ---- Kernel A: MFMA GEMM  ft(bf16-pair-packed) + el/er fused as extra cols -
__global__ __launch_bounds__(256) void k_gemm(
    const float* __restrict__ feat, const unsigned* __restrict__ wtx,
    unsigned* __restrict__ ftb2, float* __restrict__ el, float* __restrict__ er,
    int n) {
  __shared__ unsigned sB[144 * 64];  // 36864 B (uint = 2 bf16)
  const int t = threadIdx.x;
  {  // coalesced 36 KB copy, layout already swizzled
    const uint4* wx = (const uint4*)wtx;
    uint4* sx = (uint4*)sB;
    for (int it = t; it < 144 * 16; it += 256) sx[it] = wx[it];
  }
  __syncthreads();

  const int lane = t & 63;
  const int wv   = t >> 6;
  const int r0   = blockIdx.x * 128 + wv * 32;
  if (r0 >= n) return;
  const int lrow = lane & 15;
  const int lk   = lane >> 4;

  f32x4 acc[2][9];
#pragma unroll
  for (int st = 0; st < 2; ++st)
#pragma unroll
    for (int ct = 0; ct < 9; ++ct) acc[st][ct] = (f32x4)0.f;

#pragma unroll
  for (int ks = 0; ks < 4; ++ks) {
    short8 b[9];
#pragma unroll
    for (int ct = 0; ct < 9; ++ct) {
      const int row = ct * 16 + lrow;
      const int slot = ks * 4 + lk;
      b[ct] = *(const short8*)&sB[row * 64 + ((slot ^ (row & 7)) << 2)];
    }
#pragma unroll
    for (int st = 0; st < 2; ++st) {
      int arow = r0 + st * 16 + lrow;
      arow = arow < n ? arow : n - 1;
      const float* ap = feat + (size_t)arow * IN_F + ks * 32 + lk * 8;
      const float4 f0 = *(const float4*)ap;
      const float4 f1 = *(const float4*)(ap + 4);
      short8 a;
      a[0] = (short)bf16b(f0.x); a[1] = (short)bf16b(f0.y);
      a[2] = (short)bf16b(f0.z); a[3] = (short)bf16b(f0.w);
      a[4] = (short)bf16b(f1.x); a[5] = (short)bf16b(f1.y);
      a[6] = (short)bf16b(f1.z); a[7] = (short)bf16b(f1.w);
#pragma unroll
      for (int ct = 0; ct < 9; ++ct)
        acc[st][ct] = __builtin_amdgcn_mfma_f32_16x16x32_bf16(a, b[ct], acc[st][ct], 0, 0, 0);
    }
  }

#pragma unroll
  for (int st = 0; st < 2; ++st) {
#pragma unroll
    for (int i = 0; i < 4; ++i) {
      const int r = r0 + st * 16 + lk * 4 + i;
      if (r >= n) continue;
#pragma unroll
      for (int ct = 0; ct < 4; ++ct) {
        const unsigned pk = bf16b(acc[st][ct][i]) | (bf16b(acc[st][ct + 4][i]) << 16);
        ftb2[(size_t)r * 64 + ct * 16 + lrow] = pk;
      }
      if (lrow < 4)      el[r * NH + lrow]     = acc[st][8][i];
      else if (lrow < 8) er[r * NH + lrow - 4] = acc[st][8][i];
    }
  }
}

// ---- Kernel R: rank[e] = atomicAdd(deg[dst[e]],1), 4 edges/thread ---------
__global__ __launch_bounds__(256) void k_rank(
    const int* __restrict__ dst, int* __restrict__ deg, int* __restrict__ rank,
    int ne) {
  const int e4 = (blockIdx.x * 256 + threadIdx.x) * 4;
  if (e4 + 4 <= ne) {
    const int4 d = *(const int4*)(dst + e4);
    int4 r;
    r.x = atomicAdd(deg + d.x, 1);
    r.y = atomicAdd(deg + d.y, 1);
    r.z = atomicAdd(deg + d.z, 1);
    r.w = atomicAdd(deg + d.w, 1);
    *(int4*)(rank + e4) = r;
  } else {
    for (int e = e4; e < ne; ++e) rank[e] = atomicAdd(deg + dst[e], 1);
  }
}

// ---------------- Scan: exclusive prefix over deg (3 kernels) --------------
__global__ __launch_bounds__(256) void k_scan1(
    const int* __restrict__ deg, int* __restrict__ pexcl,
    int* __restrict__ bsum, int n) {
  const int t = threadIdx.x;
  const int base = blockIdx.x * 1024 + t * 4;
  int v0 = base + 0 < n ? deg[base + 0] : 0;
  int v1 = base + 1 < n ? deg[base + 1] : 0;
  int v2 = base + 2 < n ? deg[base + 2] : 0;
  int v3 = base + 3 < n ? deg[base + 3] : 0;
  const int s = v0 + v1 + v2 + v3;
  const int lane = t & 63, w = t >> 6;
  int x = s;
#pragma unroll
  for (int off = 1; off < 64; off <<= 1) {
    int y = __shfl_up(x, off);
    if (lane >= off) x += y;
  }
  __shared__ int ws[4];
  if (lane == 63) ws[w] = x;
  __syncthreads();
  int woff = 0;
  for (int i = 0; i < w; ++i) woff += ws[i];
  int run = woff + x - s;
  if (base + 0 < n) { pexcl[base + 0] = run; run += v0; }
  if (base + 1 < n) { pexcl[base + 1] = run; run += v1; }
  if (base + 2 < n) { pexcl[base + 2] = run; run += v2; }
  if (base + 3 < n) { pexcl[base + 3] = run; run += v3; }
  if (t == 0) bsum[blockIdx.x] = ws[0] + ws[1] + ws[2] + ws[3];
}

__global__ __launch_bounds__(256) void k_scan2(
    const int* __restrict__ bsum, int* __restrict__ boff, int B) {
  const int t = threadIdx.x;
  const int s = t < B ? bsum[t] : 0;
  const int lane = t & 63, w = t >> 6;
  int x = s;
#pragma unroll
  for (int off = 1; off < 64; off <<= 1) {
    int y = __shfl_up(x, off);
    if (lane >= off) x += y;
  }
  __shared__ int ws[4];
  if (lane == 63) ws[w] = x;
  __syncthreads();
  int woff = 0;
  for (int i = 0; i < w; ++i) woff += ws[i];
  if (t < B) boff[t] = woff + x - s;
}

__global__ __launch_bounds__(256) void k_scan3(
    const int* __restrict__ pexcl, const int* __restrict__ boff,
    int* __restrict__ offsets, int n, int ne) {
  const int i = blockIdx.x * 256 + threadIdx.x;
  if (i < n) offsets[i] = pexcl[i] + boff[i >> 10];
  if (i == 0) offsets[n] = ne;
}

// ---- Kernel S: scatter combined record (src, p as 4xf16) into CSR order ---
// rec[pos] = { src, half2(p0,p2), half2(p1,p3), 0 } : ONE 16B write per edge.
__global__ __launch_bounds__(256) void k_scatter(
    const int* __restrict__ src, const int* __restrict__ dst,
    const int* __restrict__ rank, const int* __restrict__ offsets,
    const float* __restrict__ el, const float* __restrict__ er,
    int4* __restrict__ rec, int ne) {
  const int e = blockIdx.x * 256 + threadIdx.x;
  if (e >= ne) return;
  const int s = src[e], d = dst[e];
  const int pos = offsets[d] + rank[e];
  const float4 l = *(const float4*)(el + (size_t)s * NH);
  const float4 r = *(const float4*)(er + (size_t)d * NH);
  float e0 = l.x + r.x, e1 = l.y + r.y, e2 = l.z + r.z, e3 = l.w + r.w;
  e0 = e0 > 0.f ? e0 : NEG_SLOPE * e0;
  e1 = e1 > 0.f ? e1 : NEG_SLOPE * e1;
  e2 = e2 > 0.f ? e2 : NEG_SLOPE * e2;
  e3 = e3 > 0.f ? e3 : NEG_SLOPE * e3;
  // |logits| <= ~8: exp() safe without segment-max; softmax ratio identical
  const __half2 h02 = __float22half2_rn(make_float2(__expf(e0), __expf(e2)));
  const __half2 h13 = __float22half2_rn(make_float2(__expf(e1), __expf(e3)));
  int4 rc;
  rc.x = s;
  rc.y = *(const int*)&h02;
  rc.z = *(const int*)&h13;
  rc.w = 0;
  rec[pos] = rc;
}

// ------ Kernel D: aggregation, one wave per dst node, 4-deep pipeline ------
__global__ __launch_bounds__(256) void k_aggr(
    const int* __restrict__ offsets, const int4* __restrict__ rec,
    const unsigned* __restrict__ ftb2, float* __restrict__ out, int n) {
  const int wid = (blockIdx.x * 256 + threadIdx.x) >> 6;
  if (wid >= n) return;
  const int lane = threadIdx.x & 63;
  const int hsel = lane >> 5;  // elem 'lane' -> head hsel; elem lane+64 -> 2+hsel
  const int start = offsets[wid], end = offsets[wid + 1];
  float acc0 = 0.f, acc1 = 0.f, den0 = 0.f, den1 = 0.f;

#define EDGE(R)                                                   \
  {                                                               \
    const int pw = hsel ? (R).z : (R).y;                          \
    const __half2 hp = *(const __half2*)&pw;                      \
    const float2 pf = __half22float2(hp);                         \
    const unsigned v = ftb2[(size_t)(R).x * 64 + lane];           \
    acc0 += __uint_as_float(v << 16) * pf.x;                      \
    acc1 += __uint_as_float(v & 0xFFFF0000u) * pf.y;              \
    den0 += pf.x;                                                 \
    den1 += pf.y;                                                 \
  }

  int i = start;
  for (; i + 4 <= end; i += 4) {
    const int4 r0 = rec[i + 0];   // 4 independent sequential loads,
    const int4 r1 = rec[i + 1];   // then 4 independent gathers
    const int4 r2 = rec[i + 2];
    const int4 r3 = rec[i + 3];
    EDGE(r0) EDGE(r1) EDGE(r2) EDGE(r3)
  }
  for (; i < end; ++i) {
    const int4 r0 = rec[i];
    EDGE(r0)
  }
#undef EDGE

  den0 = den0 > 0.f ? den0 : 1.f;  // isolated-node guard (matches reference)
  den1 = den1 > 0.f ? den1 : 1.f;
  float* orow = out + (size_t)wid * HD;
  orow[lane] = acc0 / den0;
  orow[64 + lane] = acc1 / den1;
}

extern "C" void kernel_launch(void* const* d_in, const int* in_sizes, int n_in,
                              void* d_out, int out_size, void* d_ws, size_t ws_size,
                              hipStream_t stream) {
  const float* feat   = (const float*)d_in[0];
  const float* W      = (const float*)d_in[1];
  const float* attn_l = (const float*)d_in[2];
  const float* attn_r = (const float*)d_in[3];
  const int*   src    = (const int*)d_in[4];
  const int*   dst    = (const int*)d_in[5];
  const int n  = in_sizes[0] / IN_F;
  const int ne = in_sizes[4];
  float* out = (float*)d_out;

  // workspace layout (16B-aligned blocks first)
  char* wp = (char*)d_ws;
  unsigned* ftb2    = (unsigned*)wp; wp += (size_t)n * 64 * 4;    // 25.6 MB
  int4*  rec        = (int4*)wp;     wp += (size_t)ne * 16;       // 25.6 MB
  unsigned* wtx     = (unsigned*)wp; wp += (size_t)144 * 64 * 4;  // 36 KB
  float* el         = (float*)wp;    wp += (size_t)n * NH * 4;
  float* er         = (float*)wp;    wp += (size_t)n * NH * 4;
  int*   rank       = (int*)wp;      wp += (size_t)ne * 4;
  int*   deg        = (int*)wp;      wp += (size_t)n * 4;
  int*   pexcl      = (int*)wp;      wp += (size_t)n * 4;
  int*   offsets    = (int*)wp;      wp += (size_t)(n + 1) * 4;
  int*   bsum       = (int*)wp;      wp += 256 * 4;
  int*   boff       = (int*)wp;      wp += 256 * 4;

  hipMemsetAsync(deg, 0, (size_t)n * 4, stream);

  const int B = (n + 1023) / 1024;
  k_prep<<<9, 256, 0, stream>>>(W, attn_l, attn_r, wtx);
  k_gemm<<<(n + 127) / 128, 256, 0, stream>>>(feat, wtx, ftb2, el, er, n);
  k_rank<<<(ne + 1023) / 1024, 256, 0, stream>>>(dst, deg, rank, ne);
  k_scan1<<<B, 256, 0, stream>>>(deg, pexcl, bsum, n);
  k_scan2<<<1, 256, 0, stream>>>(bsum, boff, B);
  k_scan3<<<(n + 255) / 256, 256, 0, stream>>>(pexcl, boff, offsets, n, ne);
  k_scatter<<<(ne + 255) / 256, 256, 0, stream>>>(src, dst, rank, offsets, el, er,
                                                  rec, ne);
  k_aggr<<<(n + 3) / 4, 256, 0, stream>>>(offsets, rec, ftb2, out, n);
}